// Round 1
// baseline (94.040 us; speedup 1.0000x reference)
//
#include <hip/hip_runtime.h>

#define N_KPS 1024
#define N_PTS 120000
#define BLOCK 256

// One thread per query point. Control points + TPS weights staged in LDS as
// float4 (kx, ky, wx*0.5ln2, wy*0.5ln2) so the inner loop is:
//   sub, sub, mul, fma (d2) | max, log2 (trans) | mul (v) | fma, fma (acc)
// All lanes read the same LDS word each iteration -> broadcast, no conflicts.
__global__ __launch_bounds__(BLOCK) void tps_warp_kernel(
    const float2* __restrict__ pts,
    const float*  __restrict__ kps,
    const float*  __restrict__ W,
    float2*       __restrict__ out)
{
    __shared__ float4 ctrl[N_KPS];

    // 0.5 * ln(2): folds the 0.5*l2*ln(l2) constant so inner loop uses log2.
    const float scale = 0.34657359027997264f;

    const int tid = threadIdx.x;
    #pragma unroll
    for (int i = tid; i < N_KPS; i += BLOCK) {
        float kx = kps[2 * i];
        float ky = kps[2 * i + 1];
        float wx = W[2 * i]     * scale;
        float wy = W[2 * i + 1] * scale;
        ctrl[i] = make_float4(kx, ky, wx, wy);
    }
    __syncthreads();

    const int j = blockIdx.x * BLOCK + tid;
    if (j >= N_PTS) return;

    const float2 p = pts[j];
    float zx = 0.0f, zy = 0.0f;

    #pragma unroll 8
    for (int i = 0; i < N_KPS; ++i) {
        float4 c = ctrl[i];
        float dx = c.x - p.x;
        float dy = c.y - p.y;
        float d2 = fmaf(dy, dy, dx * dx);
        // d2 == 0 -> max gives 1e-37, log2 ~ -123, v = 0 * -123 = 0,
        // matching the reference's where(l2==0, 1.0) -> 0.5*1*ln(1) = 0.
        float t  = __log2f(fmaxf(d2, 1e-37f));
        float v  = d2 * t;               // v = d2 * log2(d2); 0.5*ln2 folded into c.z/c.w
        zx = fmaf(v, c.z, zx);
        zy = fmaf(v, c.w, zy);
    }

    // Affine tail: W rows 1024 (ones), 1025 (x coeff), 1026 (y coeff) — unscaled.
    float w1x = W[2048], w1y = W[2049];
    float wxx = W[2050], wxy = W[2051];
    float wyx = W[2052], wyy = W[2053];

    float ox = p.x + zx + fmaf(wxx, p.x, fmaf(wyx, p.y, w1x));
    float oy = p.y + zy + fmaf(wxy, p.x, fmaf(wyy, p.y, w1y));
    out[j] = make_float2(ox, oy);
}

extern "C" void kernel_launch(void* const* d_in, const int* in_sizes, int n_in,
                              void* d_out, int out_size, void* d_ws, size_t ws_size,
                              hipStream_t stream) {
    const float* pts = (const float*)d_in[0];   // [120000, 2]
    const float* kps = (const float*)d_in[1];   // [1024, 2]
    const float* W   = (const float*)d_in[2];   // [1027, 2]
    float* out = (float*)d_out;                 // [120000, 2]

    const int grid = (N_PTS + BLOCK - 1) / BLOCK;
    tps_warp_kernel<<<grid, BLOCK, 0, stream>>>(
        (const float2*)pts, kps, W, (float2*)out);
}

// Round 2
// 93.339 us; speedup vs baseline: 1.0075x; 1.0075x over previous
//
#include <hip/hip_runtime.h>

#define N_KPS 1024
#define N_PTS 120000
#define BLOCK 64

// One wave per block, one thread per query point, 1875 blocks (exact cover).
// Control-point data (kps, W) is wave-uniform per iteration -> compiler emits
// scalar s_load_dwordx8/x16 into SGPRs (constant cache). Zero LDS: round 1 was
// co-limited by LDS broadcast return bandwidth (64 lanes x 16B per ds_read_b128
// ~ 8 cyc/CU each; 8 waves/CU demanded ~2.6x the LDS service rate).
// Inner loop: 2 sub, mul, fma (d2) | max, v_log_f32 | mul | 2 fma  = 8 VALU + 1 trans.
__global__ __launch_bounds__(BLOCK) void tps_warp_kernel(
    const float2* __restrict__ pts,
    const float*  __restrict__ kps,
    const float*  __restrict__ W,
    float2*       __restrict__ out)
{
    const int j = blockIdx.x * BLOCK + threadIdx.x;  // 1875*64 == 120000 exactly
    const float2 p = pts[j];

    float zx = 0.0f, zy = 0.0f;

    #pragma unroll 16
    for (int i = 0; i < N_KPS; ++i) {
        // Uniform-index loads -> SGPRs; the compiler merges adjacent ones.
        float kx = kps[2 * i];
        float ky = kps[2 * i + 1];
        float wx = W[2 * i];
        float wy = W[2 * i + 1];
        float dx = kx - p.x;
        float dy = ky - p.y;
        float d2 = fmaf(dy, dy, dx * dx);
        // d2 == 0 -> max gives 1e-37, log2 ~ -123, v = 0 * -123 = 0,
        // matching reference's where(l2==0, 1.0) -> 0.5*1*ln(1) = 0.
        float t  = __log2f(fmaxf(d2, 1e-37f));
        float v  = d2 * t;                 // d2 * log2(d2); 0.5*ln2 applied once at the end
        zx = fmaf(v, wx, zx);
        zy = fmaf(v, wy, zy);
    }

    const float scale = 0.34657359027997264f;  // 0.5 * ln(2)

    // Affine tail: W rows 1024 (ones), 1025 (x coeff), 1026 (y coeff).
    float w1x = W[2048], w1y = W[2049];
    float wxx = W[2050], wxy = W[2051];
    float wyx = W[2052], wyy = W[2053];

    float ox = p.x + fmaf(scale, zx, fmaf(wxx, p.x, fmaf(wyx, p.y, w1x)));
    float oy = p.y + fmaf(scale, zy, fmaf(wxy, p.x, fmaf(wyy, p.y, w1y)));
    out[j] = make_float2(ox, oy);
}

extern "C" void kernel_launch(void* const* d_in, const int* in_sizes, int n_in,
                              void* d_out, int out_size, void* d_ws, size_t ws_size,
                              hipStream_t stream) {
    const float* pts = (const float*)d_in[0];   // [120000, 2]
    const float* kps = (const float*)d_in[1];   // [1024, 2]
    const float* W   = (const float*)d_in[2];   // [1027, 2]
    float* out = (float*)d_out;                 // [120000, 2]

    const int grid = N_PTS / BLOCK;  // 1875, exact
    tps_warp_kernel<<<grid, BLOCK, 0, stream>>>(
        (const float2*)pts, kps, W, (float2*)out);
}

// Round 3
// 88.394 us; speedup vs baseline: 1.0639x; 1.0559x over previous
//
#include <hip/hip_runtime.h>

#define N_KPS 1024
#define N_PTS 120000
#define BLOCK 256           // 4 waves per block
#define KSPLIT 4            // one wave per K-chunk (TLP fix: 3752 waves vs 1875)
#define KCHUNK (N_KPS / KSPLIT)   // 256
#define PTS_PER_BLOCK 128   // 64 lanes x 2 points/thread

typedef float v2f __attribute__((ext_vector_type(2)));

// Round-2 post-mortem: limiter was latency hiding (1.83 waves/SIMD, VALUBusy 58%).
// This version: (a) split-K x4 -> 3.66 waves/SIMD; (b) 2 query points per thread
// packed into v_pk_*_f32 ops -> 4 VALU + 1 trans issue-cycles-equivalent per pair
// (was 8+1), and 2x independent v_log_f32 chains per unrolled iteration.
__global__ __launch_bounds__(BLOCK) void tps_warp_kernel(
    const float2* __restrict__ pts,
    const float*  __restrict__ kps,
    const float*  __restrict__ W,
    float2*       __restrict__ out)
{
    __shared__ float4 part[KSPLIT][64];

    const int lane = threadIdx.x & 63;
    const int kch  = threadIdx.x >> 6;            // 0..3 (wave id)
    const int base = blockIdx.x * PTS_PER_BLOCK;
    const int j0 = base + lane;
    const int j1 = base + 64 + lane;

    // Clamp loads for the tail block (stores predicated below).
    const int j0c = j0 < N_PTS ? j0 : N_PTS - 1;
    const int j1c = j1 < N_PTS ? j1 : N_PTS - 1;
    const float2 p0 = pts[j0c];
    const float2 p1 = pts[j1c];

    v2f px = {p0.x, p1.x};
    v2f py = {p0.y, p1.y};
    v2f zx = {0.0f, 0.0f};
    v2f zy = {0.0f, 0.0f};
    const v2f tiny = {1e-37f, 1e-37f};

    const int k0 = kch * KCHUNK;
    #pragma unroll 4
    for (int i = k0; i < k0 + KCHUNK; ++i) {
        // Wave-uniform -> scalar loads through the constant cache.
        float kx = kps[2 * i];
        float ky = kps[2 * i + 1];
        float wx = W[2 * i];
        float wy = W[2 * i + 1];
        v2f kxv = {kx, kx}, kyv = {ky, ky};
        v2f wxv = {wx, wx}, wyv = {wy, wy};

        v2f dx = kxv - px;                              // v_pk_add (neg mod)
        v2f dy = kyv - py;
        v2f d2 = __builtin_elementwise_fma(dy, dy, dx * dx);   // pk_mul + pk_fma
        // d2==0 -> clamp to 1e-37: v = 1e-37 * log2(1e-37) ~ -1e-35 ~ 0,
        // matching reference's where(l2==0,1.0) -> 0.5*1*ln(1) = 0.
        d2 = __builtin_elementwise_max(d2, tiny);       // v_pk_max_f32
        v2f t;
        t.x = __log2f(d2.x);                            // v_log_f32 (trans)
        t.y = __log2f(d2.y);
        v2f v = d2 * t;                                 // pk_mul; 0.5*ln2 folded at end
        zx = __builtin_elementwise_fma(v, wxv, zx);     // pk_fma
        zy = __builtin_elementwise_fma(v, wyv, zy);     // pk_fma
    }

    part[kch][lane] = make_float4(zx.x, zy.x, zx.y, zy.y);
    __syncthreads();

    if (kch == 0) {
        float4 a = part[0][lane];
        float4 b = part[1][lane];
        float4 c = part[2][lane];
        float4 d = part[3][lane];
        float sx0 = (a.x + b.x) + (c.x + d.x);
        float sy0 = (a.y + b.y) + (c.y + d.y);
        float sx1 = (a.z + b.z) + (c.z + d.z);
        float sy1 = (a.w + b.w) + (c.w + d.w);

        const float scale = 0.34657359027997264f;  // 0.5 * ln(2)
        float w1x = W[2048], w1y = W[2049];
        float wxx = W[2050], wxy = W[2051];
        float wyx = W[2052], wyy = W[2053];

        if (j0 < N_PTS) {
            float ox = p0.x + fmaf(scale, sx0, fmaf(wxx, p0.x, fmaf(wyx, p0.y, w1x)));
            float oy = p0.y + fmaf(scale, sy0, fmaf(wxy, p0.x, fmaf(wyy, p0.y, w1y)));
            out[j0] = make_float2(ox, oy);
        }
        if (j1 < N_PTS) {
            float ox = p1.x + fmaf(scale, sx1, fmaf(wxx, p1.x, fmaf(wyx, p1.y, w1x)));
            float oy = p1.y + fmaf(scale, sy1, fmaf(wxy, p1.x, fmaf(wyy, p1.y, w1y)));
            out[j1] = make_float2(ox, oy);
        }
    }
}

extern "C" void kernel_launch(void* const* d_in, const int* in_sizes, int n_in,
                              void* d_out, int out_size, void* d_ws, size_t ws_size,
                              hipStream_t stream) {
    const float* pts = (const float*)d_in[0];   // [120000, 2]
    const float* kps = (const float*)d_in[1];   // [1024, 2]
    const float* W   = (const float*)d_in[2];   // [1027, 2]
    float* out = (float*)d_out;                 // [120000, 2]

    const int grid = (N_PTS + PTS_PER_BLOCK - 1) / PTS_PER_BLOCK;  // 938
    tps_warp_kernel<<<grid, BLOCK, 0, stream>>>(
        (const float2*)pts, kps, W, (float2*)out);
}

// Round 4
// 82.527 us; speedup vs baseline: 1.1395x; 1.0711x over previous
//
#include <hip/hip_runtime.h>

#define N_KPS 1024
#define N_PTS 120000
#define BLOCK 512                  // 8 waves per block
#define KSPLIT 8                   // one wave per K-chunk
#define KCHUNK (N_KPS / KSPLIT)    // 128 control points per wave
#define PTS_PER_BLOCK 128          // 64 lanes x 2 points/thread
#define CHUNK 8                    // ctrl points per pipelined chunk
#define NCHUNK (KCHUNK / CHUNK)    // 16

typedef float v2f __attribute__((ext_vector_type(2)));

// r3 post-mortem: k0 = f(threadIdx.x>>6) is divergent to LLVM -> kps/W reads
// became per-lane vector loads; ~200cyc vmcnt waits with ~2 waves/SIMD = 49%
// stall. Fixes: (a) readfirstlane forces the wave id into an SGPR so control
// data loads are s_load_dwordx4 (scalar, no per-lane latency); (b) explicit
// next-chunk prefetch so each s_waitcnt lands after a ~160-cycle compute body;
// (c) 8 waves/block x 938 blocks = 7.3 waves/SIMD for real latency hiding.
__global__ __launch_bounds__(BLOCK) void tps_warp_kernel(
    const float2* __restrict__ pts,
    const float*  __restrict__ kps,
    const float*  __restrict__ W,
    float2*       __restrict__ out)
{
    __shared__ float4 part[KSPLIT][64];

    const int lane = threadIdx.x & 63;
    // Provably wave-uniform wave id -> SGPR -> scalar loads for kps/W.
    const int wv = __builtin_amdgcn_readfirstlane(threadIdx.x) >> 6;

    const int base = blockIdx.x * PTS_PER_BLOCK;
    const int j0 = base + lane;
    const int j1 = base + 64 + lane;
    const int j0c = j0 < N_PTS ? j0 : N_PTS - 1;
    const int j1c = j1 < N_PTS ? j1 : N_PTS - 1;
    const float2 p0 = pts[j0c];
    const float2 p1 = pts[j1c];

    v2f px = {p0.x, p1.x};
    v2f py = {p0.y, p1.y};
    v2f zx = {0.0f, 0.0f};
    v2f zy = {0.0f, 0.0f};
    const v2f tiny = {1e-37f, 1e-37f};

    auto eval = [&](float kx, float ky, float wx, float wy) {
        v2f dx = v2f{kx, kx} - px;
        v2f dy = v2f{ky, ky} - py;
        v2f d2 = __builtin_elementwise_fma(dy, dy, dx * dx);
        // d2==0 -> clamp: v = 1e-37*log2(1e-37) ~ 0, matching reference's
        // where(l2==0, 1.0) -> 0.5*1*ln(1) = 0.
        d2 = __builtin_elementwise_max(d2, tiny);
        v2f t;
        t.x = __log2f(d2.x);
        t.y = __log2f(d2.y);
        v2f v = d2 * t;                      // 0.5*ln2 folded in at the end
        zx = __builtin_elementwise_fma(v, v2f{wx, wx}, zx);
        zy = __builtin_elementwise_fma(v, v2f{wy, wy}, zy);
    };

    // Control data as float4 pairs: kp4[t] = {kx,ky,kx,ky}, wp4[t] = {wx,wy,wx,wy}.
    const float4* __restrict__ kp4 = (const float4*)kps;   // 512 entries
    const float4* __restrict__ wp4 = (const float4*)W;
    const int cbase = wv * (KCHUNK / 2);                   // float4 index base

    // Prime chunk 0.
    float4 kc[4], wc[4];
    #pragma unroll
    for (int t = 0; t < 4; ++t) {
        kc[t] = kp4[cbase + t];
        wc[t] = wp4[cbase + t];
    }

    for (int c = 0; c < NCHUNK; ++c) {
        // Prefetch next chunk (clamped re-read on the last iteration — K$ hit).
        const int nc = (c + 1 < NCHUNK) ? c + 1 : c;
        float4 kn[4], wn[4];
        #pragma unroll
        for (int t = 0; t < 4; ++t) {
            kn[t] = kp4[cbase + nc * 4 + t];
            wn[t] = wp4[cbase + nc * 4 + t];
        }
        // Compute current chunk: 8 ctrl pts x 2 packed points = 16 logs in flight.
        #pragma unroll
        for (int t = 0; t < 4; ++t) {
            eval(kc[t].x, kc[t].y, wc[t].x, wc[t].y);
            eval(kc[t].z, kc[t].w, wc[t].z, wc[t].w);
        }
        #pragma unroll
        for (int t = 0; t < 4; ++t) {
            kc[t] = kn[t];
            wc[t] = wn[t];
        }
    }

    part[wv][lane] = make_float4(zx.x, zy.x, zx.y, zy.y);
    __syncthreads();

    if (wv == 0) {
        float sx0 = 0.f, sy0 = 0.f, sx1 = 0.f, sy1 = 0.f;
        #pragma unroll
        for (int w = 0; w < KSPLIT; w += 2) {   // pairwise-ish tree
            float4 a = part[w][lane];
            float4 b = part[w + 1][lane];
            sx0 += a.x + b.x;
            sy0 += a.y + b.y;
            sx1 += a.z + b.z;
            sy1 += a.w + b.w;
        }

        const float scale = 0.34657359027997264f;  // 0.5 * ln(2)
        float w1x = W[2048], w1y = W[2049];
        float wxx = W[2050], wxy = W[2051];
        float wyx = W[2052], wyy = W[2053];

        if (j0 < N_PTS) {
            float ox = p0.x + fmaf(scale, sx0, fmaf(wxx, p0.x, fmaf(wyx, p0.y, w1x)));
            float oy = p0.y + fmaf(scale, sy0, fmaf(wxy, p0.x, fmaf(wyy, p0.y, w1y)));
            out[j0] = make_float2(ox, oy);
        }
        if (j1 < N_PTS) {
            float ox = p1.x + fmaf(scale, sx1, fmaf(wxx, p1.x, fmaf(wyx, p1.y, w1x)));
            float oy = p1.y + fmaf(scale, sy1, fmaf(wxy, p1.x, fmaf(wyy, p1.y, w1y)));
            out[j1] = make_float2(ox, oy);
        }
    }
}

extern "C" void kernel_launch(void* const* d_in, const int* in_sizes, int n_in,
                              void* d_out, int out_size, void* d_ws, size_t ws_size,
                              hipStream_t stream) {
    const float* pts = (const float*)d_in[0];   // [120000, 2]
    const float* kps = (const float*)d_in[1];   // [1024, 2]
    const float* W   = (const float*)d_in[2];   // [1027, 2]
    float* out = (float*)d_out;                 // [120000, 2]

    const int grid = (N_PTS + PTS_PER_BLOCK - 1) / PTS_PER_BLOCK;  // 938
    tps_warp_kernel<<<grid, BLOCK, 0, stream>>>(
        (const float2*)pts, kps, W, (float2*)out);
}